// Round 5
// baseline (99.017 us; speedup 1.0000x reference)
//
#include <hip/hip_runtime.h>
#include <stdint.h>

// ---------------------------------------------------------------------------
// CnnPatchDropout: out[b,c,h,w] = mask[b, pq] ? embed[pq,c,kh,kw] : batch[...]
// mask derived from jax.random.key(42) via threefry2x32 (partitionable).
// B=64,C=64,H=W=128,KH=KW=8,HP=WP=16,PQ=256. Verified bit-exact (round 1).
//
// Ladder so far:
//   R1: 1 float4/thread, cached ld/st              101.7 us
//   R3: +nt-load +nt-store +unroll16                108.7 us (nt-load kills
//       cross-replay L3 residency of batch)
//   R4: R1 + nt-store only                           92.0 us (confirmed)
//   R5 (this): R4 + ITEMS=4 grid-stride ILP — 4 mask loads, then 4 data
//       loads in flight per thread, then 4 nt-stores.
// ---------------------------------------------------------------------------

#define BB 64
#define PQ 256

#define MAIN_THREADS 256
#define MAIN_ITEMS 4
#define MAIN_BLOCKS 16384                    // 16384*256*4 == 16,777,216 exactly
#define MAIN_STRIDE (MAIN_BLOCKS * MAIN_THREADS)

// native vector type: __builtin_nontemporal_* rejects HIP_vector_type struct
typedef float f32x4 __attribute__((ext_vector_type(4)));

__device__ __forceinline__ uint32_t rotl32(uint32_t v, int r) {
  return (v << r) | (v >> (32 - r));
}

// JAX threefry2x32 block: key (k0,k1), counter (x0,x1).
__device__ __forceinline__ void tf2x32(uint32_t k0, uint32_t k1,
                                       uint32_t x0, uint32_t x1,
                                       uint32_t& o0, uint32_t& o1) {
  uint32_t ks2 = k0 ^ k1 ^ 0x1BD11BDAu;
  x0 += k0; x1 += k1;
#define TFR(r) { x0 += x1; x1 = rotl32(x1, (r)); x1 ^= x0; }
  TFR(13) TFR(15) TFR(26) TFR(6)   x0 += k1;  x1 += ks2 + 1u;
  TFR(17) TFR(29) TFR(16) TFR(24)  x0 += ks2; x1 += k0  + 2u;
  TFR(13) TFR(15) TFR(26) TFR(6)   x0 += k0;  x1 += k1  + 3u;
  TFR(17) TFR(29) TFR(16) TFR(24)  x0 += k1;  x1 += ks2 + 4u;
  TFR(13) TFR(15) TFR(26) TFR(6)   x0 += ks2; x1 += k0  + 5u;
#undef TFR
  o0 = x0; o1 = x1;
}

// Partitionable random_bits (32-bit): XOR-fold the two cipher outputs.
__device__ __forceinline__ uint32_t tf_fold(uint32_t k0, uint32_t k1,
                                            uint32_t c_hi, uint32_t c_lo) {
  uint32_t a, b;
  tf2x32(k0, k1, c_hi, c_lo, a, b);
  return a ^ b;
}

// uniform[0,1): bitcast((bits>>9)|0x3f800000) - 1.0f
__device__ __forceinline__ float bits_to_unif(uint32_t bits) {
  return __uint_as_float((bits >> 9) | 0x3f800000u) - 1.0f;
}

// One block per image b: mask[b][0..255].
__global__ __launch_bounds__(256) void mask_kernel(unsigned char* __restrict__ mask) {
  __shared__ uint32_t keybits[PQ];
  __shared__ int s_dropped;
  __shared__ int s_apply;

  const int b = blockIdx.x;
  const int p = threadIdx.x;

  // split(key(42), 3): k_i = full TF output pair at counter (0, i).
  uint32_t k3a, k3b; tf2x32(0u, 42u, 0u, 2u, k3a, k3b);

  // r[b,p] mantissa-order bits (monotone proxy for the uniform float)
  const uint32_t rb = tf_fold(k3a, k3b, 0u, (uint32_t)(b * PQ + p)) >> 9;
  keybits[p] = rb;

  if (p == 0) {
    uint32_t k1a, k1b; tf2x32(0u, 42u, 0u, 0u, k1a, k1b);
    uint32_t k2a, k2b; tf2x32(0u, 42u, 0u, 1u, k2a, k2b);
    float u1 = bits_to_unif(tf_fold(k1a, k1b, 0u, (uint32_t)b));
    float u2 = bits_to_unif(tf_fold(k2a, k2b, 0u, (uint32_t)b));
    s_apply = (u1 < 0.5f) ? 1 : 0;
    float frac = u2 * 0.4f;   // separate mul then add: mirror XLA (no FMA)
    frac = frac + 0.1f;
    s_dropped = (int)floorf(frac * 256.0f);
  }
  __syncthreads();

  // stable rank of r[b,p] within row b == argsort(argsort(r))[b,p]
  int rank = 0;
  for (int q = 0; q < PQ; ++q) {
    uint32_t o = keybits[q];           // broadcast read: conflict-free
    rank += (o < rb) || (o == rb && q < p);
  }
  mask[b * PQ + p] = (s_apply && rank < s_dropped) ? 1 : 0;
}

// Main copy/select. 4 float4 per thread, grid-stride (perfect coalescing),
// phase-ordered for MLP: 4 mask loads -> 4 data loads -> 4 nt-stores.
// Cached loads (batch ~L3-resident across replays); non-temporal stores.
__global__ __launch_bounds__(MAIN_THREADS) void patch_dropout_kernel(
    const f32x4* __restrict__ batch,
    const f32x4* __restrict__ embed,
    const unsigned char* __restrict__ mask,
    f32x4* __restrict__ out) {
  const int tid = blockIdx.x * MAIN_THREADS + threadIdx.x;

  int idx[MAIN_ITEMS];
  unsigned char m[MAIN_ITEMS];
  int eidx[MAIN_ITEMS];

  // phase 1: indices + mask bytes (L1/L2-resident, 16 KB table)
#pragma unroll
  for (int k = 0; k < MAIN_ITEMS; ++k) {
    const int i = tid + k * MAIN_STRIDE;
    idx[k] = i;
    // i indexes float4s: w4=i&31 (W/4=32), h=(i>>5)&127, c=(i>>12)&63, b=i>>18
    const int w4 = i & 31;
    const int h  = (i >> 5) & 127;
    const int c  = (i >> 12) & 63;
    const int b  = i >> 18;
    const int pq = ((h >> 3) << 4) | (w4 >> 1);   // hp*16 + wp
    // embed flat float idx = pq*4096 + c*64 + kh*8 + kw ; /4 -> float4 idx
    eidx[k] = (pq << 10) + (c << 4) + ((h & 7) << 1) + (w4 & 1);
    m[k] = mask[(b << 8) | pq];
  }

  // phase 2: data loads — up to 4 independent requests in flight
  f32x4 v[MAIN_ITEMS];
#pragma unroll
  for (int k = 0; k < MAIN_ITEMS; ++k) {
    v[k] = m[k] ? embed[eidx[k]] : batch[idx[k]];
  }

  // phase 3: non-temporal stores (touch-once stream, keep out of L2/L3)
#pragma unroll
  for (int k = 0; k < MAIN_ITEMS; ++k) {
    __builtin_nontemporal_store(v[k], &out[idx[k]]);
  }
}

extern "C" void kernel_launch(void* const* d_in, const int* in_sizes, int n_in,
                              void* d_out, int out_size, void* d_ws, size_t ws_size,
                              hipStream_t stream) {
  const float* batch = (const float*)d_in[0];
  const float* embed = (const float*)d_in[1];
  float* out = (float*)d_out;
  unsigned char* mask = (unsigned char*)d_ws;   // 16 KB scratch

  mask_kernel<<<BB, 256, 0, stream>>>(mask);

  patch_dropout_kernel<<<MAIN_BLOCKS, MAIN_THREADS, 0, stream>>>(
      (const f32x4*)batch, (const f32x4*)embed, mask, (f32x4*)out);
}

// Round 6
// 94.711 us; speedup vs baseline: 1.0455x; 1.0455x over previous
//
#include <hip/hip_runtime.h>
#include <stdint.h>

// ---------------------------------------------------------------------------
// CnnPatchDropout: out[b,c,h,w] = mask[b, pq] ? embed[pq,c,kh,kw] : batch[...]
// mask derived from jax.random.key(42) via threefry2x32 (partitionable).
// B=64,C=64,H=W=128,KH=KW=8,HP=WP=16,PQ=256. Verified bit-exact (round 1).
//
// Ladder:
//   R1: 1 float4/thread, cached ld/st                         101.7 us
//   R3: +nt-load +nt-store +unroll16 (grid-stride)            108.7 us
//       (nt-load kills cross-replay L3 residency of batch)
//   R4: R1 + nt-store only                                     92.0 us  BEST
//   R5: R4 + ITEMS=4 grid-stride (64MB-apart per-thread)       99.0 us
//       (page-locality destroyed; traffic counters unchanged)
//   R6 (this): R4 + ITEMS=4 block-contiguous — block owns 16KB
//       contiguous; thread items 4KB apart; 4 loads in flight.
// ---------------------------------------------------------------------------

#define BB 64
#define PQ 256

#define MAIN_THREADS 256
#define MAIN_ITEMS 4
#define MAIN_BLOCKS 16384            // 16384 * 1024 float4 == 16,777,216 exactly
#define BLOCK_SPAN (MAIN_THREADS * MAIN_ITEMS)   // 1024 float4 per block

// native vector type: __builtin_nontemporal_* rejects HIP_vector_type struct
typedef float f32x4 __attribute__((ext_vector_type(4)));

__device__ __forceinline__ uint32_t rotl32(uint32_t v, int r) {
  return (v << r) | (v >> (32 - r));
}

// JAX threefry2x32 block: key (k0,k1), counter (x0,x1).
__device__ __forceinline__ void tf2x32(uint32_t k0, uint32_t k1,
                                       uint32_t x0, uint32_t x1,
                                       uint32_t& o0, uint32_t& o1) {
  uint32_t ks2 = k0 ^ k1 ^ 0x1BD11BDAu;
  x0 += k0; x1 += k1;
#define TFR(r) { x0 += x1; x1 = rotl32(x1, (r)); x1 ^= x0; }
  TFR(13) TFR(15) TFR(26) TFR(6)   x0 += k1;  x1 += ks2 + 1u;
  TFR(17) TFR(29) TFR(16) TFR(24)  x0 += ks2; x1 += k0  + 2u;
  TFR(13) TFR(15) TFR(26) TFR(6)   x0 += k0;  x1 += k1  + 3u;
  TFR(17) TFR(29) TFR(16) TFR(24)  x0 += k1;  x1 += ks2 + 4u;
  TFR(13) TFR(15) TFR(26) TFR(6)   x0 += ks2; x1 += k0  + 5u;
#undef TFR
  o0 = x0; o1 = x1;
}

// Partitionable random_bits (32-bit): XOR-fold the two cipher outputs.
__device__ __forceinline__ uint32_t tf_fold(uint32_t k0, uint32_t k1,
                                            uint32_t c_hi, uint32_t c_lo) {
  uint32_t a, b;
  tf2x32(k0, k1, c_hi, c_lo, a, b);
  return a ^ b;
}

// uniform[0,1): bitcast((bits>>9)|0x3f800000) - 1.0f
__device__ __forceinline__ float bits_to_unif(uint32_t bits) {
  return __uint_as_float((bits >> 9) | 0x3f800000u) - 1.0f;
}

// One block per image b: mask[b][0..255].
__global__ __launch_bounds__(256) void mask_kernel(unsigned char* __restrict__ mask) {
  __shared__ uint32_t keybits[PQ];
  __shared__ int s_dropped;
  __shared__ int s_apply;

  const int b = blockIdx.x;
  const int p = threadIdx.x;

  // split(key(42), 3): k_i = full TF output pair at counter (0, i).
  uint32_t k3a, k3b; tf2x32(0u, 42u, 0u, 2u, k3a, k3b);

  // r[b,p] mantissa-order bits (monotone proxy for the uniform float)
  const uint32_t rb = tf_fold(k3a, k3b, 0u, (uint32_t)(b * PQ + p)) >> 9;
  keybits[p] = rb;

  if (p == 0) {
    uint32_t k1a, k1b; tf2x32(0u, 42u, 0u, 0u, k1a, k1b);
    uint32_t k2a, k2b; tf2x32(0u, 42u, 0u, 1u, k2a, k2b);
    float u1 = bits_to_unif(tf_fold(k1a, k1b, 0u, (uint32_t)b));
    float u2 = bits_to_unif(tf_fold(k2a, k2b, 0u, (uint32_t)b));
    s_apply = (u1 < 0.5f) ? 1 : 0;
    float frac = u2 * 0.4f;   // separate mul then add: mirror XLA (no FMA)
    frac = frac + 0.1f;
    s_dropped = (int)floorf(frac * 256.0f);
  }
  __syncthreads();

  // stable rank of r[b,p] within row b == argsort(argsort(r))[b,p]
  int rank = 0;
  for (int q = 0; q < PQ; ++q) {
    uint32_t o = keybits[q];           // broadcast read: conflict-free
    rank += (o < rb) || (o == rb && q < p);
  }
  mask[b * PQ + p] = (s_apply && rank < s_dropped) ? 1 : 0;
}

// Main copy/select. Block owns 1024 CONSECUTIVE float4 (16KB contiguous);
// thread handles base + it*256 + tid for it=0..3 (items 4KB apart). Wave
// coalescing per instruction unchanged; 4 independent loads in flight per
// thread before the first store waits. Cached loads (batch ~L3-resident
// across replays); non-temporal stores (touch-once).
__global__ __launch_bounds__(MAIN_THREADS) void patch_dropout_kernel(
    const f32x4* __restrict__ batch,
    const f32x4* __restrict__ embed,
    const unsigned char* __restrict__ mask,
    f32x4* __restrict__ out) {
  const int base = blockIdx.x * BLOCK_SPAN + threadIdx.x;

  f32x4 v[MAIN_ITEMS];
#pragma unroll
  for (int k = 0; k < MAIN_ITEMS; ++k) {
    const int i = base + k * MAIN_THREADS;
    // i indexes float4s: w4=i&31 (W/4=32), h=(i>>5)&127, c=(i>>12)&63, b=i>>18
    const int w4 = i & 31;
    const int h  = (i >> 5) & 127;
    const int c  = (i >> 12) & 63;
    const int b  = i >> 18;
    const int pq = ((h >> 3) << 4) | (w4 >> 1);   // hp*16 + wp

    if (mask[(b << 8) | pq]) {
      // embed flat float idx = pq*4096 + c*64 + kh*8 + kw ; /4 -> float4 idx
      v[k] = embed[(pq << 10) + (c << 4) + ((h & 7) << 1) + (w4 & 1)];
    } else {
      v[k] = batch[i];
    }
  }

#pragma unroll
  for (int k = 0; k < MAIN_ITEMS; ++k) {
    __builtin_nontemporal_store(v[k], &out[base + k * MAIN_THREADS]);
  }
}

extern "C" void kernel_launch(void* const* d_in, const int* in_sizes, int n_in,
                              void* d_out, int out_size, void* d_ws, size_t ws_size,
                              hipStream_t stream) {
  const float* batch = (const float*)d_in[0];
  const float* embed = (const float*)d_in[1];
  float* out = (float*)d_out;
  unsigned char* mask = (unsigned char*)d_ws;   // 16 KB scratch

  mask_kernel<<<BB, 256, 0, stream>>>(mask);

  patch_dropout_kernel<<<MAIN_BLOCKS, MAIN_THREADS, 0, stream>>>(
      (const f32x4*)batch, (const f32x4*)embed, mask, (f32x4*)out);
}

// Round 7
// 94.227 us; speedup vs baseline: 1.0508x; 1.0051x over previous
//
#include <hip/hip_runtime.h>
#include <stdint.h>

// ---------------------------------------------------------------------------
// CnnPatchDropout: out[b,c,h,w] = mask[b, pq] ? embed[pq,c,kh,kw] : batch[...]
// mask derived from jax.random.key(42) via threefry2x32 (partitionable).
// B=64,C=64,H=W=128,KH=KW=8,HP=WP=16,PQ=256. Verified bit-exact (round 1).
//
// Ladder:
//   R1: 1 float4/thread, cached ld/st                         101.7 us
//   R3: +nt-load +nt-store +unroll16 (grid-stride)            108.7 us
//   R4: R1 + nt-store only                                     92.0 us  BEST
//   R5: R4 + ITEMS=4 grid-stride ILP                           99.0 us
//   R6: R4 + ITEMS=4 block-contiguous ILP                      94.7 us
//       -> not latency-bound; main kernel ~94% of copy ceiling.
//   R7 (this): FUSE mask computation into the main kernel (single launch,
//       R4 geometry). Block = 256 consecutive float4 = one hp-row of one
//       (b,c) plane -> needs 16 mask values; recompute them block-locally
//       in LDS (thread0: apply/dropped; all: 256 r-values; 16x16 rank
//       + shfl_xor reduce). Removes mask-kernel launch + inter-launch drain.
// ---------------------------------------------------------------------------

#define PQ 256
#define MAIN_THREADS 256
#define MAIN_BLOCKS 65536            // 65536 * 256 float4 == 16,777,216 exactly

// native vector type: __builtin_nontemporal_* rejects HIP_vector_type struct
typedef float f32x4 __attribute__((ext_vector_type(4)));

__device__ __forceinline__ uint32_t rotl32(uint32_t v, int r) {
  return (v << r) | (v >> (32 - r));
}

// JAX threefry2x32 block: key (k0,k1), counter (x0,x1).
__device__ __forceinline__ void tf2x32(uint32_t k0, uint32_t k1,
                                       uint32_t x0, uint32_t x1,
                                       uint32_t& o0, uint32_t& o1) {
  uint32_t ks2 = k0 ^ k1 ^ 0x1BD11BDAu;
  x0 += k0; x1 += k1;
#define TFR(r) { x0 += x1; x1 = rotl32(x1, (r)); x1 ^= x0; }
  TFR(13) TFR(15) TFR(26) TFR(6)   x0 += k1;  x1 += ks2 + 1u;
  TFR(17) TFR(29) TFR(16) TFR(24)  x0 += ks2; x1 += k0  + 2u;
  TFR(13) TFR(15) TFR(26) TFR(6)   x0 += k0;  x1 += k1  + 3u;
  TFR(17) TFR(29) TFR(16) TFR(24)  x0 += k1;  x1 += ks2 + 4u;
  TFR(13) TFR(15) TFR(26) TFR(6)   x0 += ks2; x1 += k0  + 5u;
#undef TFR
  o0 = x0; o1 = x1;
}

// Partitionable random_bits (32-bit): XOR-fold the two cipher outputs.
__device__ __forceinline__ uint32_t tf_fold(uint32_t k0, uint32_t k1,
                                            uint32_t c_hi, uint32_t c_lo) {
  uint32_t a, b;
  tf2x32(k0, k1, c_hi, c_lo, a, b);
  return a ^ b;
}

// uniform[0,1): bitcast((bits>>9)|0x3f800000) - 1.0f
__device__ __forceinline__ float bits_to_unif(uint32_t bits) {
  return __uint_as_float((bits >> 9) | 0x3f800000u) - 1.0f;
}

// Fused kernel. Block covers 256 consecutive float4 starting at
// base = blockIdx.x*256: b = base>>18 fixed, c fixed, 8 aligned h-rows
// -> single hp row, patches pq = hp0*16 + wp, wp = 0..15.
__global__ __launch_bounds__(MAIN_THREADS) void patch_dropout_fused(
    const f32x4* __restrict__ batch,
    const f32x4* __restrict__ embed,
    f32x4* __restrict__ out) {
  __shared__ uint32_t keybits[PQ];
  __shared__ int s_m[16];            // per-wp select flag (int: 1 bank each)
  __shared__ int s_apply, s_dropped;

  const int tid  = threadIdx.x;
  const int base = blockIdx.x * MAIN_THREADS;
  const int i    = base + tid;
  const int b    = i >> 18;
  const int hp0  = ((base >> 5) & 127) >> 3;

  if (tid == 0) {
    // split(key(42),3): k_i = TF output pair at counter (0,i)
    uint32_t k1a, k1b; tf2x32(0u, 42u, 0u, 0u, k1a, k1b);
    uint32_t k2a, k2b; tf2x32(0u, 42u, 0u, 1u, k2a, k2b);
    float u1 = bits_to_unif(tf_fold(k1a, k1b, 0u, (uint32_t)b));
    float u2 = bits_to_unif(tf_fold(k2a, k2b, 0u, (uint32_t)b));
    s_apply = (u1 < 0.5f) ? 1 : 0;
    float frac = u2 * 0.4f;          // separate mul then add: mirror XLA
    frac = frac + 0.1f;
    s_dropped = (int)floorf(frac * 256.0f);
  }
  __syncthreads();

  if (s_apply) {                     // block-uniform branch
    // all 256 r-values of image b (1 threefry per thread)
    uint32_t k3a, k3b; tf2x32(0u, 42u, 0u, 2u, k3a, k3b);
    keybits[tid] = tf_fold(k3a, k3b, 0u, (uint32_t)(b * PQ + tid)) >> 9;
    __syncthreads();

    // rank the 16 needed patches: patch j ranked by 16 threads, 16 cmp each
    const int j = tid >> 4;          // 0..15
    const int k = tid & 15;
    const int pqj = (hp0 << 4) | j;
    const uint32_t rp = keybits[pqj];
    int part = 0;
#pragma unroll
    for (int qq = 0; qq < 16; ++qq) {
      const int q = (k << 4) | qq;
      const uint32_t o = keybits[q];
      part += (o < rp) || (o == rp && q < pqj);
    }
    // sum over the 16-lane group (xor masks < 16 stay within group)
    part += __shfl_xor(part, 1);
    part += __shfl_xor(part, 2);
    part += __shfl_xor(part, 4);
    part += __shfl_xor(part, 8);
    if (k == 0) s_m[j] = (part < s_dropped) ? 1 : 0;
    __syncthreads();
  } else {
    if (tid < 16) s_m[tid] = 0;
    __syncthreads();
  }

  // main copy/select (R4 schedule: cached loads, nt-store)
  const int w4 = i & 31;
  const int h  = (i >> 5) & 127;
  const int c  = (i >> 12) & 63;
  const int wp = w4 >> 1;

  f32x4 v;
  if (s_m[wp]) {
    const int pq = (hp0 << 4) | wp;
    // embed flat float idx = pq*4096 + c*64 + kh*8 + kw ; /4 -> float4 idx
    v = embed[(pq << 10) + (c << 4) + ((h & 7) << 1) + (w4 & 1)];
  } else {
    v = batch[i];
  }
  __builtin_nontemporal_store(v, &out[i]);
}

extern "C" void kernel_launch(void* const* d_in, const int* in_sizes, int n_in,
                              void* d_out, int out_size, void* d_ws, size_t ws_size,
                              hipStream_t stream) {
  const float* batch = (const float*)d_in[0];
  const float* embed = (const float*)d_in[1];
  float* out = (float*)d_out;
  (void)d_ws; (void)ws_size; (void)in_sizes; (void)n_in; (void)out_size;

  patch_dropout_fused<<<MAIN_BLOCKS, MAIN_THREADS, 0, stream>>>(
      (const f32x4*)batch, (const f32x4*)embed, (f32x4*)out);
}

// Round 8
// 92.002 us; speedup vs baseline: 1.0762x; 1.0242x over previous
//
#include <hip/hip_runtime.h>
#include <stdint.h>

// ---------------------------------------------------------------------------
// CnnPatchDropout: out[b,c,h,w] = mask[b, pq] ? embed[pq,c,kh,kw] : batch[...]
// mask derived from jax.random.key(42) via threefry2x32 (partitionable).
// B=64,C=64,H=W=128,KH=KW=8,HP=WP=16,PQ=256. Verified bit-exact (round 1).
//
// Ladder (final):
//   R1: 1 float4/thread, cached ld/st                         101.7 us
//   R3: +nt-load +nt-store +unroll16 (grid-stride)            108.7 us
//       (nt-load kills cross-replay L3 residency of batch)
//   R4: R1 + nt-store only                                     92.0 us  BEST
//   R5: R4 + ITEMS=4 grid-stride ILP                           99.0 us
//   R6: R4 + ITEMS=4 block-contiguous ILP                      94.7 us
//   R7: fused mask+copy single launch                          94.2 us
//       (mask prologue barriers delay load issue > launch saved)
//   R8 (this): revert to R4 — the measured optimum. Main kernel runs at
//       ~92% of the 6.29 TB/s copy ceiling (495 MB apparent / ~86 us);
//       remaining gap is mixed read/write DRAM turnaround (write-only
//       fill hits 6.9 TB/s; traffic counters identical across R4-R7).
// ---------------------------------------------------------------------------

#define BB 64
#define PQ 256

// native vector type: __builtin_nontemporal_* rejects HIP_vector_type struct
typedef float f32x4 __attribute__((ext_vector_type(4)));

__device__ __forceinline__ uint32_t rotl32(uint32_t v, int r) {
  return (v << r) | (v >> (32 - r));
}

// JAX threefry2x32 block: key (k0,k1), counter (x0,x1).
__device__ __forceinline__ void tf2x32(uint32_t k0, uint32_t k1,
                                       uint32_t x0, uint32_t x1,
                                       uint32_t& o0, uint32_t& o1) {
  uint32_t ks2 = k0 ^ k1 ^ 0x1BD11BDAu;
  x0 += k0; x1 += k1;
#define TFR(r) { x0 += x1; x1 = rotl32(x1, (r)); x1 ^= x0; }
  TFR(13) TFR(15) TFR(26) TFR(6)   x0 += k1;  x1 += ks2 + 1u;
  TFR(17) TFR(29) TFR(16) TFR(24)  x0 += ks2; x1 += k0  + 2u;
  TFR(13) TFR(15) TFR(26) TFR(6)   x0 += k0;  x1 += k1  + 3u;
  TFR(17) TFR(29) TFR(16) TFR(24)  x0 += k1;  x1 += ks2 + 4u;
  TFR(13) TFR(15) TFR(26) TFR(6)   x0 += ks2; x1 += k0  + 5u;
#undef TFR
  o0 = x0; o1 = x1;
}

// Partitionable random_bits (32-bit): XOR-fold the two cipher outputs.
__device__ __forceinline__ uint32_t tf_fold(uint32_t k0, uint32_t k1,
                                            uint32_t c_hi, uint32_t c_lo) {
  uint32_t a, b;
  tf2x32(k0, k1, c_hi, c_lo, a, b);
  return a ^ b;
}

// uniform[0,1): bitcast((bits>>9)|0x3f800000) - 1.0f
__device__ __forceinline__ float bits_to_unif(uint32_t bits) {
  return __uint_as_float((bits >> 9) | 0x3f800000u) - 1.0f;
}

// One block per image b: mask[b][0..255].
__global__ __launch_bounds__(256) void mask_kernel(unsigned char* __restrict__ mask) {
  __shared__ uint32_t keybits[PQ];
  __shared__ int s_dropped;
  __shared__ int s_apply;

  const int b = blockIdx.x;
  const int p = threadIdx.x;

  // split(key(42), 3): k_i = full TF output pair at counter (0, i).
  uint32_t k3a, k3b; tf2x32(0u, 42u, 0u, 2u, k3a, k3b);

  // r[b,p] mantissa-order bits (monotone proxy for the uniform float)
  const uint32_t rb = tf_fold(k3a, k3b, 0u, (uint32_t)(b * PQ + p)) >> 9;
  keybits[p] = rb;

  if (p == 0) {
    uint32_t k1a, k1b; tf2x32(0u, 42u, 0u, 0u, k1a, k1b);
    uint32_t k2a, k2b; tf2x32(0u, 42u, 0u, 1u, k2a, k2b);
    float u1 = bits_to_unif(tf_fold(k1a, k1b, 0u, (uint32_t)b));
    float u2 = bits_to_unif(tf_fold(k2a, k2b, 0u, (uint32_t)b));
    s_apply = (u1 < 0.5f) ? 1 : 0;
    float frac = u2 * 0.4f;   // separate mul then add: mirror XLA (no FMA)
    frac = frac + 0.1f;
    s_dropped = (int)floorf(frac * 256.0f);
  }
  __syncthreads();

  // stable rank of r[b,p] within row b == argsort(argsort(r))[b,p]
  int rank = 0;
  for (int q = 0; q < PQ; ++q) {
    uint32_t o = keybits[q];           // broadcast read: conflict-free
    rank += (o < rb) || (o == rb && q < p);
  }
  mask[b * PQ + p] = (s_apply && rank < s_dropped) ? 1 : 0;
}

// Main copy/select. One float4 per thread (proven optimum). Cached loads
// (batch is ~L3-resident across graph replays); non-temporal store only
// (touch-once write stream stays out of L2/L3, freeing cache for reads).
__global__ __launch_bounds__(256) void patch_dropout_kernel(
    const f32x4* __restrict__ batch,
    const f32x4* __restrict__ embed,
    const unsigned char* __restrict__ mask,
    f32x4* __restrict__ out, int n4) {
  int i = blockIdx.x * blockDim.x + threadIdx.x;
  if (i >= n4) return;
  // i indexes float4s: w4 = i&31 (W/4=32), h = (i>>5)&127, c = (i>>12)&63, b = i>>18
  const int w4 = i & 31;
  const int h  = (i >> 5) & 127;
  const int c  = (i >> 12) & 63;
  const int b  = i >> 18;
  const int pq = ((h >> 3) << 4) | (w4 >> 1);   // hp*16 + wp

  f32x4 v;
  if (mask[(b << 8) | pq]) {
    // embed flat float idx = pq*4096 + c*64 + kh*8 + kw ; /4 -> float4 idx
    v = embed[(pq << 10) + (c << 4) + ((h & 7) << 1) + (w4 & 1)];
  } else {
    v = batch[i];
  }
  __builtin_nontemporal_store(v, &out[i]);
}

extern "C" void kernel_launch(void* const* d_in, const int* in_sizes, int n_in,
                              void* d_out, int out_size, void* d_ws, size_t ws_size,
                              hipStream_t stream) {
  const float* batch = (const float*)d_in[0];
  const float* embed = (const float*)d_in[1];
  float* out = (float*)d_out;
  unsigned char* mask = (unsigned char*)d_ws;   // 16 KB scratch

  mask_kernel<<<BB, 256, 0, stream>>>(mask);

  const int n4 = out_size / 4;                  // 16,777,216
  const int blocks = (n4 + 255) / 256;          // 65,536
  patch_dropout_kernel<<<blocks, 256, 0, stream>>>(
      (const f32x4*)batch, (const f32x4*)embed, mask, (f32x4*)out, n4);
}